// Round 18
// baseline (78.528 us; speedup 1.0000x reference)
//
#include <hip/hip_runtime.h>

namespace {
constexpr int kH = 192, kW = 640, kHW = kH * kW;
constexpr int kW4g = kW / 4;            // 160 granules per row
constexpr int kHW4 = kHW / 4;           // 30720 granules per plane
constexpr int kB = 2, kC = 64;          // batch, image channels
constexpr int kN0 = 40000, kC0 = 32;    // level0 points/channels
constexpr int kN1 = 20000, kC1 = 64;    // level1 points/channels
constexpr int kCL = 67;                 // C1 + 3
constexpr int kBHW = kB * kHW;
// zero-padded y planes: 18 = 9 taps x B, rows H+2, pitch W+8 (interior at +1,+4)
constexpr int kPH = kH + 2, kPW = kW + 8;  // 194 x 648
constexpr int kPW4 = kPW / 4;              // 162
constexpr int kPlane = kPH * kPW;          // 125712
constexpr int kYPF = 18 * kPlane;
constexpr int kWin4 = 2 * kBHW / 4;        // win01 int2 array as int4 pairs
// border float4s per plane: row0 (162) + row193 (162) + 192 rows x {col0,col161}
constexpr int kBord = 162 + 162 + 192 * 2;  // 708
constexpr int kBordTot = 18 * kBord;        // 12744
// K2 block partition: gate FIRST (BW-critical), then scatter, then precomp
constexpr int kGateB = kB * kHW4 / 64;      // 960 gate blocks
constexpr int kScatB0 = kGateB;             // scatter starts at 960
constexpr int kScatB = 469;                 // ceil(120000/256)
constexpr int kPrecB = kScatB0 + kScatB;    // 1429 = precomp block
// kpass2 partition: 240 granule-chunks x 2 channel-halves
constexpr int kChunks = kB * kHW4 / 256;    // 240

typedef float vf4 __attribute__((ext_vector_type(4)));

// ---------------------------------------------------------------------------
// init: zero ONLY the padded-y borders (interior is fully rewritten by kgy
// each replay) and fill the interleaved winner map with -1.
// ---------------------------------------------------------------------------
__global__ __launch_bounds__(256) void kinit(float* __restrict__ yp,
                                             int4* __restrict__ win4) {
  int i = blockIdx.x * 256 + threadIdx.x;
  if (i < kBordTot) {
    int plane = i / kBord, r = i - plane * kBord;
    float4* base = (float4*)(yp + (size_t)plane * kPlane);
    int f4;
    if (r < 162) {
      f4 = r;                                  // row 0
    } else if (r < 324) {
      f4 = 193 * kPW4 + (r - 162);             // row 193
    } else {
      int rr = r - 324;
      int row = 1 + (rr >> 1);
      f4 = row * kPW4 + ((rr & 1) ? (kPW4 - 1) : 0);  // cols 0-3 / 644-647
    }
    base[f4] = make_float4(0.f, 0.f, 0.f, 0.f);
  } else {
    int j = i - kBordTot;
    if (j < kWin4) win4[j] = make_int4(-1, -1, -1, -1);
  }
}

// ---------------------------------------------------------------------------
// K2 (heterogeneous; gate first so the BW-critical 63 MB stream opens at
// dispatch time, scatter+precomp hide in its tail):
//   blocks [0,960): gate -> single summed g plane. Block = 64 granules;
//        256 thr = 64 granules x 4 chunks of 16 ch; LDS-reduce (fixed order).
//   blocks [960,1429): winner scatter into interleaved win01 (int2/pixel,
//        last-write-wins == max index wins)
//   block 1429: LDS-staged fold: b'=W2@b0+b2; A1=Wsp^T@W2; M0=A1@W0;
//        sb_k=Wsp[:,k].b'; wsum_k=sum_c Wsp[c,k]
// ---------------------------------------------------------------------------
__global__ __launch_bounds__(256) void k2(
    const float* __restrict__ coor0, const float* __restrict__ coor1,
    int* __restrict__ win01,
    const float* __restrict__ W0, const float* __restrict__ b0,
    const float* __restrict__ W2, const float* __restrict__ b2,
    const float* __restrict__ Wsp, float* __restrict__ M0,
    float* __restrict__ A1g, float* __restrict__ sb, float* __restrict__ wsum,
    const float* __restrict__ x_rgb, const float* __restrict__ W3,
    float* __restrict__ g) {
  __shared__ float W2s[kCL * kCL];
  __shared__ float W0s[kCL * 35];
  __shared__ float Wsps[kCL * 9];
  __shared__ float A1s[9 * kCL];
  __shared__ float bps[kCL];
  const int bid = blockIdx.x;
  const int t = threadIdx.x;
  if (bid < kGateB) {  // ---- gate ----
    __shared__ float4 part[4][64];
    const int gg = t & 63, q = t >> 6;
    const int gran = bid * 64 + gg;
    const int b = gran / kHW4;
    const int p4 = gran - b * kHW4;
    const float4* xr = (const float4*)(x_rgb + (size_t)b * kC * kHW) + p4;
    float4 acc = make_float4(0.f, 0.f, 0.f, 0.f);
#pragma unroll
    for (int cc = 0; cc < 16; ++cc) {
      const int c = q * 16 + cc;
      float wv = W3[c];
      float4 x4 = xr[(size_t)c * kHW4];
      acc.x += wv * x4.x;
      acc.y += wv * x4.y;
      acc.z += wv * x4.z;
      acc.w += wv * x4.w;
    }
    part[q][gg] = acc;
    __syncthreads();
    if (t < 64) {
      float4 p0 = part[0][t], p1 = part[1][t], p2 = part[2][t],
             p3 = part[3][t];
      float4 s;
      s.x = p0.x + p1.x + p2.x + p3.x;
      s.y = p0.y + p1.y + p2.y + p3.y;
      s.z = p0.z + p1.z + p2.z + p3.z;
      s.w = p0.w + p1.w + p2.w + p3.w;
      ((float4*)g)[bid * 64 + t] = s;
    }
    return;
  }
  if (bid < kPrecB) {  // ---- scatter ----
    int idx = (bid - kScatB0) * 256 + t;
    const float* coor;
    int lvl, N;
    if (idx < kB * kN0) {
      coor = coor0; lvl = 0; N = kN0;
    } else {
      idx -= kB * kN0;
      if (idx >= kB * kN1) return;
      coor = coor1; lvl = 1; N = kN1;
    }
    int b = idx / N;
    float u = coor[(size_t)idx * 2 + 0];
    float v = coor[(size_t)idx * 2 + 1];
    u = fminf(fmaxf(u, 0.f), 1.f);
    v = fminf(fmaxf(v, 0.f), 1.f);
    int r = (int)(v * (float)kH);  // row from coor[:,1]
    int c = (int)(u * (float)kW);  // col from coor[:,0]
    if (r < kH && c < kW) {
      int n = idx - b * N;
      atomicMax(&win01[2 * (b * kHW + r * kW + c) + lvl], n);
    }
    return;
  }
  // ---- precomp (block 1429, LDS-staged) ----
  for (int i = t; i < kCL * kCL; i += 256) W2s[i] = W2[i];
  for (int i = t; i < kCL * 35; i += 256) W0s[i] = W0[i];
  for (int i = t; i < kCL * 9; i += 256) Wsps[i] = Wsp[i];
  __syncthreads();
  if (t < kCL) {
    float s = b2[t];
    for (int j = 0; j < kCL; ++j) s += W2s[t * kCL + j] * b0[j];
    bps[t] = s;
  }
  for (int idx = t; idx < 9 * kCL; idx += 256) {
    int k = idx / kCL, j = idx - k * kCL;
    float s = 0.f;
    for (int c = 0; c < kCL; ++c) s += Wsps[c * 9 + k] * W2s[c * kCL + j];
    A1s[idx] = s;
    A1g[idx] = s;
  }
  __syncthreads();
  for (int idx = t; idx < 9 * 35; idx += 256) {
    int k = idx / 35, i = idx - k * 35;
    float s = 0.f;
    for (int j = 0; j < kCL; ++j) s += A1s[k * kCL + j] * W0s[j * 35 + i];
    M0[idx] = s;
  }
  if (t < 9) {
    float s = 0.f;
    for (int c = 0; c < kCL; ++c) s += Wsps[c * 9 + t] * bps[c];
    sb[t] = s;
  } else if (t >= 16 && t < 25) {
    int k = t - 16;
    float s = 0.f;
    for (int c = 0; c < kCL; ++c) s += Wsps[c * 9 + k];
    wsum[k] = s;
  }
}

// ---------------------------------------------------------------------------
// kgy (single-pass 9-tap): 960 blocks, 1 px/thread, no barriers.
// Everything fetched ONCE per pixel (g, winners, feats); all 9 tap
// projections computed from the same registers; 9 plane-coalesced stores.
// (r18 A/B vs the 3-way tap-split: 1/3 the gather traffic and per-pixel
// overhead at 1/3 the block count.)
// ---------------------------------------------------------------------------
__global__ __launch_bounds__(256) void kgy(
    const float* __restrict__ g, const int2* __restrict__ win01,
    const float* __restrict__ feat0, const float* __restrict__ vox0,
    const float* __restrict__ feat1, const float* __restrict__ vox1,
    const float* __restrict__ M0, const float* __restrict__ A1,
    const float* __restrict__ sb, const float* __restrict__ wsum,
    const float* __restrict__ b3, float* __restrict__ yp) {
  const int pix = blockIdx.x * 256 + threadIdx.x;
  const int b = pix / kHW;
  const int pp = pix - b * kHW;
  const int h = pp / kW;
  const int w = pp - h * kW;
  const float gv = b3[0] + g[pix];
  float y[9];
#pragma unroll
  for (int k = 0; k < 9; ++k) y[k] = wsum[k] * gv + sb[k];

  const int2 wv2 = win01[pix];
  const int w0 = wv2.x;
  if (w0 >= 0) {
    const float4* f0 = (const float4*)(feat0 + ((size_t)b * kN0 + w0) * kC0);
#pragma unroll
    for (int i4 = 0; i4 < 8; ++i4) {
      float4 v = f0[i4];
#pragma unroll
      for (int k = 0; k < 9; ++k) {
        const float* m = M0 + k * 35 + i4 * 4;
        y[k] += m[0] * v.x + m[1] * v.y + m[2] * v.z + m[3] * v.w;
      }
    }
    const float* v0 = vox0 + ((size_t)b * kN0 + w0) * 3;
#pragma unroll
    for (int i = 0; i < 3; ++i) {
      float v = v0[i];
#pragma unroll
      for (int k = 0; k < 9; ++k) y[k] += M0[k * 35 + kC0 + i] * v;
    }
  }
  const int w1 = wv2.y;
  if (w1 >= 0) {
    const float4* f1 = (const float4*)(feat1 + ((size_t)b * kN1 + w1) * kC1);
#pragma unroll
    for (int i4 = 0; i4 < 16; ++i4) {
      float4 v = f1[i4];
#pragma unroll
      for (int k = 0; k < 9; ++k) {
        const float* m = A1 + k * kCL + i4 * 4;
        y[k] += m[0] * v.x + m[1] * v.y + m[2] * v.z + m[3] * v.w;
      }
    }
    const float* v1 = vox1 + ((size_t)b * kN1 + w1) * 3;
#pragma unroll
    for (int i = 0; i < 3; ++i) {
      float v = v1[i];
#pragma unroll
      for (int k = 0; k < 9; ++k) y[k] += A1[k * kCL + kC1 + i] * v;
    }
  }
#pragma unroll
  for (int k = 0; k < 9; ++k) {
    yp[((size_t)(k * kB + b) * kPH + (h + 1)) * kPW + 4 + w] = y[k];
  }
}

// ---------------------------------------------------------------------------
// fused stencil+sigmoid+multiply, att-in-register:
// block <-> (256-granule chunk, channel HALF). thread <-> granule.
// x loads plain (L3-resident after k2); out stores nontemporal.
// ---------------------------------------------------------------------------
__global__ __launch_bounds__(256) void kpass2(const float* __restrict__ x_rgb,
                                              const float* __restrict__ yp,
                                              const float* __restrict__ bsp,
                                              float* __restrict__ out) {
  const int bid = blockIdx.x;
  const int q = bid / kChunks;         // channel half 0..1 (uniform/block)
  const int chunk = bid - q * kChunks;
  const int gran = chunk * 256 + threadIdx.x;
  const int b = gran / kHW4;
  const int p4 = gran - b * kHW4;
  const int h = p4 / kW4g;
  const int w4 = p4 - h * kW4g;

  const float bias = bsp[0];
  float4 lg = make_float4(bias, bias, bias, bias);
#pragma unroll
  for (int r = 0; r < 3; ++r) {
    const size_t rowoff = ((size_t)h + r) * kPW + 4 * w4;
    const float* pA = yp + (size_t)((3 * r + 0) * kB + b) * kPlane + rowoff;
    const float* pB = yp + (size_t)((3 * r + 1) * kB + b) * kPlane + rowoff;
    const float* pC = yp + (size_t)((3 * r + 2) * kB + b) * kPlane + rowoff;
    float LA = pA[3];
    float4 a4 = *(const float4*)(pA + 4);
    float4 b4 = *(const float4*)(pB + 4);
    float4 c4 = *(const float4*)(pC + 4);
    float RC = pC[8];
    lg.x += LA + b4.x + c4.y;
    lg.y += a4.x + b4.y + c4.z;
    lg.z += a4.y + b4.z + c4.w;
    lg.w += a4.z + b4.w + RC;
  }
  float4 att;
  att.x = 1.f / (1.f + __expf(-lg.x));
  att.y = 1.f / (1.f + __expf(-lg.y));
  att.z = 1.f / (1.f + __expf(-lg.z));
  att.w = 1.f / (1.f + __expf(-lg.w));

  const float4* xr = (const float4*)(x_rgb + (size_t)b * kC * kHW) + p4;
  vf4* op = (vf4*)(out + (size_t)b * kC * kHW) + p4;
#pragma unroll
  for (int cc = 0; cc < 32; ++cc) {
    const int c = q * 32 + cc;
    float4 x4 = xr[(size_t)c * kHW4];
    vf4 r4;
    r4.x = x4.x * att.x;
    r4.y = x4.y * att.y;
    r4.z = x4.z * att.z;
    r4.w = x4.w * att.w;
    __builtin_nontemporal_store(r4, op + (size_t)c * kHW4);
  }
}

}  // namespace

extern "C" void kernel_launch(void* const* d_in, const int* in_sizes, int n_in,
                              void* d_out, int out_size, void* d_ws,
                              size_t ws_size, hipStream_t stream) {
  const float* x_rgb = (const float*)d_in[0];
  const float* feat0 = (const float*)d_in[1];
  const float* coor0 = (const float*)d_in[2];
  const float* vox0 = (const float*)d_in[3];
  const float* feat1 = (const float*)d_in[4];
  const float* coor1 = (const float*)d_in[5];
  const float* vox1 = (const float*)d_in[6];
  const float* W0 = (const float*)d_in[7];
  const float* b0 = (const float*)d_in[8];
  const float* W2 = (const float*)d_in[9];
  const float* b2 = (const float*)d_in[10];
  const float* W3 = (const float*)d_in[11];
  const float* b3 = (const float*)d_in[12];
  const float* Wsp = (const float*)d_in[13];
  const float* bsp = (const float*)d_in[14];
  float* out = (float*)d_out;

  // workspace: yp[18*194*648] | g[BHW] | win01[2*BHW] | M0 | A1 | sb | wsum
  float* yp = (float*)d_ws;
  float* g = yp + (size_t)kYPF;
  int* win01 = (int*)(g + (size_t)kBHW);
  float* M0 = (float*)(win01 + (size_t)2 * kBHW);
  float* A1 = M0 + 9 * 35;
  float* sb = A1 + 9 * kCL;
  float* wsum = sb + 9;

  const int ninit = kBordTot + kWin4;
  kinit<<<(ninit + 255) / 256, 256, 0, stream>>>(yp, (int4*)win01);
  k2<<<kPrecB + 1, 256, 0, stream>>>(coor0, coor1, win01, W0, b0, W2, b2, Wsp,
                                     M0, A1, sb, wsum, x_rgb, W3, g);
  kgy<<<kBHW / 256, 256, 0, stream>>>(g, (const int2*)win01, feat0, vox0,
                                      feat1, vox1, M0, A1, sb, wsum, b3, yp);
  kpass2<<<2 * kChunks, 256, 0, stream>>>(x_rgb, yp, bsp, out);
}

// Round 19
// 71.480 us; speedup vs baseline: 1.0986x; 1.0986x over previous
//
#include <hip/hip_runtime.h>

namespace {
constexpr int kH = 192, kW = 640, kHW = kH * kW;
constexpr int kW4g = kW / 4;            // 160 granules per row
constexpr int kHW4 = kHW / 4;           // 30720 granules per plane
constexpr int kB = 2, kC = 64;          // batch, image channels
constexpr int kN0 = 40000, kC0 = 32;    // level0 points/channels
constexpr int kN1 = 20000, kC1 = 64;    // level1 points/channels
constexpr int kCL = 67;                 // C1 + 3
constexpr int kBHW = kB * kHW;
// zero-padded y planes: 18 = 9 taps x B, rows H+2, pitch W+8 (interior at +1,+4)
constexpr int kPH = kH + 2, kPW = kW + 8;  // 194 x 648
constexpr int kPW4 = kPW / 4;              // 162
constexpr int kPlane = kPH * kPW;          // 125712
constexpr int kYPF = 18 * kPlane;
constexpr int kWin4 = 2 * kBHW / 4;        // win01 int2 array as int4 pairs
// border float4s per plane: row0 (162) + row193 (162) + 192 rows x {col0,col161}
constexpr int kBord = 162 + 162 + 192 * 2;  // 708
constexpr int kBordTot = 18 * kBord;        // 12744
// K2 block partition: gate FIRST (BW-critical), then scatter, then precomp
constexpr int kGateB = kB * kHW4 / 64;      // 960 gate blocks
constexpr int kScatB0 = kGateB;             // scatter starts at 960
constexpr int kScatB = 469;                 // ceil(120000/256)
constexpr int kPrecB = kScatB0 + kScatB;    // 1429 = precomp block
// kpass2 partition: 240 granule-chunks x 2 channel-halves
constexpr int kChunks = kB * kHW4 / 256;    // 240

typedef float vf4 __attribute__((ext_vector_type(4)));

// ---------------------------------------------------------------------------
// init: zero ONLY the padded-y borders (interior is fully rewritten by kgy
// each replay) and fill the interleaved winner map with -1.
// ---------------------------------------------------------------------------
__global__ __launch_bounds__(256) void kinit(float* __restrict__ yp,
                                             int4* __restrict__ win4) {
  int i = blockIdx.x * 256 + threadIdx.x;
  if (i < kBordTot) {
    int plane = i / kBord, r = i - plane * kBord;
    float4* base = (float4*)(yp + (size_t)plane * kPlane);
    int f4;
    if (r < 162) {
      f4 = r;                                  // row 0
    } else if (r < 324) {
      f4 = 193 * kPW4 + (r - 162);             // row 193
    } else {
      int rr = r - 324;
      int row = 1 + (rr >> 1);
      f4 = row * kPW4 + ((rr & 1) ? (kPW4 - 1) : 0);  // cols 0-3 / 644-647
    }
    base[f4] = make_float4(0.f, 0.f, 0.f, 0.f);
  } else {
    int j = i - kBordTot;
    if (j < kWin4) win4[j] = make_int4(-1, -1, -1, -1);
  }
}

// ---------------------------------------------------------------------------
// K2 (heterogeneous; gate first so the BW-critical 63 MB stream opens at
// dispatch time, scatter+precomp hide in its tail):
//   blocks [0,960): gate -> single summed g plane. Block = 64 granules;
//        256 thr = 64 granules x 4 chunks of 16 ch; LDS-reduce (fixed order).
//   blocks [960,1429): winner scatter into interleaved win01 (int2/pixel,
//        last-write-wins == max index wins)
//   block 1429: LDS-staged fold: b'=W2@b0+b2; A1=Wsp^T@W2; M0=A1@W0;
//        sb_k=Wsp[:,k].b'; wsum_k=sum_c Wsp[c,k]
// ---------------------------------------------------------------------------
__global__ __launch_bounds__(256) void k2(
    const float* __restrict__ coor0, const float* __restrict__ coor1,
    int* __restrict__ win01,
    const float* __restrict__ W0, const float* __restrict__ b0,
    const float* __restrict__ W2, const float* __restrict__ b2,
    const float* __restrict__ Wsp, float* __restrict__ M0,
    float* __restrict__ A1g, float* __restrict__ sb, float* __restrict__ wsum,
    const float* __restrict__ x_rgb, const float* __restrict__ W3,
    float* __restrict__ g) {
  __shared__ float W2s[kCL * kCL];
  __shared__ float W0s[kCL * 35];
  __shared__ float Wsps[kCL * 9];
  __shared__ float A1s[9 * kCL];
  __shared__ float bps[kCL];
  const int bid = blockIdx.x;
  const int t = threadIdx.x;
  if (bid < kGateB) {  // ---- gate ----
    __shared__ float4 part[4][64];
    const int gg = t & 63, q = t >> 6;
    const int gran = bid * 64 + gg;
    const int b = gran / kHW4;
    const int p4 = gran - b * kHW4;
    const float4* xr = (const float4*)(x_rgb + (size_t)b * kC * kHW) + p4;
    float4 acc = make_float4(0.f, 0.f, 0.f, 0.f);
#pragma unroll
    for (int cc = 0; cc < 16; ++cc) {
      const int c = q * 16 + cc;
      float wv = W3[c];
      float4 x4 = xr[(size_t)c * kHW4];
      acc.x += wv * x4.x;
      acc.y += wv * x4.y;
      acc.z += wv * x4.z;
      acc.w += wv * x4.w;
    }
    part[q][gg] = acc;
    __syncthreads();
    if (t < 64) {
      float4 p0 = part[0][t], p1 = part[1][t], p2 = part[2][t],
             p3 = part[3][t];
      float4 s;
      s.x = p0.x + p1.x + p2.x + p3.x;
      s.y = p0.y + p1.y + p2.y + p3.y;
      s.z = p0.z + p1.z + p2.z + p3.z;
      s.w = p0.w + p1.w + p2.w + p3.w;
      ((float4*)g)[bid * 64 + t] = s;
    }
    return;
  }
  if (bid < kPrecB) {  // ---- scatter ----
    int idx = (bid - kScatB0) * 256 + t;
    const float* coor;
    int lvl, N;
    if (idx < kB * kN0) {
      coor = coor0; lvl = 0; N = kN0;
    } else {
      idx -= kB * kN0;
      if (idx >= kB * kN1) return;
      coor = coor1; lvl = 1; N = kN1;
    }
    int b = idx / N;
    float u = coor[(size_t)idx * 2 + 0];
    float v = coor[(size_t)idx * 2 + 1];
    u = fminf(fmaxf(u, 0.f), 1.f);
    v = fminf(fmaxf(v, 0.f), 1.f);
    int r = (int)(v * (float)kH);  // row from coor[:,1]
    int c = (int)(u * (float)kW);  // col from coor[:,0]
    if (r < kH && c < kW) {
      int n = idx - b * N;
      atomicMax(&win01[2 * (b * kHW + r * kW + c) + lvl], n);
    }
    return;
  }
  // ---- precomp (block 1429, LDS-staged) ----
  for (int i = t; i < kCL * kCL; i += 256) W2s[i] = W2[i];
  for (int i = t; i < kCL * 35; i += 256) W0s[i] = W0[i];
  for (int i = t; i < kCL * 9; i += 256) Wsps[i] = Wsp[i];
  __syncthreads();
  if (t < kCL) {
    float s = b2[t];
    for (int j = 0; j < kCL; ++j) s += W2s[t * kCL + j] * b0[j];
    bps[t] = s;
  }
  for (int idx = t; idx < 9 * kCL; idx += 256) {
    int k = idx / kCL, j = idx - k * kCL;
    float s = 0.f;
    for (int c = 0; c < kCL; ++c) s += Wsps[c * 9 + k] * W2s[c * kCL + j];
    A1s[idx] = s;
    A1g[idx] = s;
  }
  __syncthreads();
  for (int idx = t; idx < 9 * 35; idx += 256) {
    int k = idx / 35, i = idx - k * 35;
    float s = 0.f;
    for (int j = 0; j < kCL; ++j) s += A1s[k * kCL + j] * W0s[j * 35 + i];
    M0[idx] = s;
  }
  if (t < 9) {
    float s = 0.f;
    for (int c = 0; c < kCL; ++c) s += Wsps[c * 9 + t] * bps[c];
    sb[t] = s;
  } else if (t >= 16 && t < 25) {
    int k = t - 16;
    float s = 0.f;
    for (int c = 0; c < kCL; ++c) s += Wsps[c * 9 + k];
    wsum[k] = s;
  }
}

// ---------------------------------------------------------------------------
// tap projection for taps [KBASE, KBASE+NK): everything compile-time-unrolled.
// FP order per (pixel,tap) identical to the 3-way r17 version.
// ---------------------------------------------------------------------------
template <int KBASE, int NK>
__device__ __forceinline__ void tap_project(
    int pix, int b, int h, int w, float gv, const int2* __restrict__ win01,
    const float* __restrict__ feat0, const float* __restrict__ vox0,
    const float* __restrict__ feat1, const float* __restrict__ vox1,
    const float* __restrict__ M0, const float* __restrict__ A1,
    const float* __restrict__ sb, const float* __restrict__ wsum,
    float* __restrict__ yp) {
  float y[NK];
#pragma unroll
  for (int kk = 0; kk < NK; ++kk)
    y[kk] = wsum[KBASE + kk] * gv + sb[KBASE + kk];

  const int2 wv2 = win01[pix];
  const int w0 = wv2.x;
  if (w0 >= 0) {
    const float4* f0 = (const float4*)(feat0 + ((size_t)b * kN0 + w0) * kC0);
#pragma unroll
    for (int i4 = 0; i4 < 8; ++i4) {
      float4 v = f0[i4];
#pragma unroll
      for (int kk = 0; kk < NK; ++kk) {
        const float* m = M0 + (KBASE + kk) * 35 + i4 * 4;
        y[kk] += m[0] * v.x + m[1] * v.y + m[2] * v.z + m[3] * v.w;
      }
    }
    const float* v0 = vox0 + ((size_t)b * kN0 + w0) * 3;
#pragma unroll
    for (int i = 0; i < 3; ++i) {
      float v = v0[i];
#pragma unroll
      for (int kk = 0; kk < NK; ++kk)
        y[kk] += M0[(KBASE + kk) * 35 + kC0 + i] * v;
    }
  }
  const int w1 = wv2.y;
  if (w1 >= 0) {
    const float4* f1 = (const float4*)(feat1 + ((size_t)b * kN1 + w1) * kC1);
#pragma unroll
    for (int i4 = 0; i4 < 16; ++i4) {
      float4 v = f1[i4];
#pragma unroll
      for (int kk = 0; kk < NK; ++kk) {
        const float* m = A1 + (KBASE + kk) * kCL + i4 * 4;
        y[kk] += m[0] * v.x + m[1] * v.y + m[2] * v.z + m[3] * v.w;
      }
    }
    const float* v1 = vox1 + ((size_t)b * kN1 + w1) * 3;
#pragma unroll
    for (int i = 0; i < 3; ++i) {
      float v = v1[i];
#pragma unroll
      for (int kk = 0; kk < NK; ++kk)
        y[kk] += A1[(KBASE + kk) * kCL + kC1 + i] * v;
    }
  }
#pragma unroll
  for (int kk = 0; kk < NK; ++kk) {
    yp[((size_t)((KBASE + kk) * kB + b) * kPH + (h + 1)) * kPW + 4 + w] =
        y[kk];
  }
}

// ---------------------------------------------------------------------------
// kgy: 2-way tap split (1920 blocks). tg=0 -> taps 0..3, tg=1 -> taps 4..8.
// r18 A/B showed 960 blocks (1-way) is latency-starved (+9.7us) while 2880
// (3-way) works; 2-way probes the middle: 2x redundancy at 1920 blocks.
// ---------------------------------------------------------------------------
__global__ __launch_bounds__(256) void kgy(
    const float* __restrict__ g, const int2* __restrict__ win01,
    const float* __restrict__ feat0, const float* __restrict__ vox0,
    const float* __restrict__ feat1, const float* __restrict__ vox1,
    const float* __restrict__ M0, const float* __restrict__ A1,
    const float* __restrict__ sb, const float* __restrict__ wsum,
    const float* __restrict__ b3, float* __restrict__ yp) {
  const int blk = blockIdx.x;
  const int tg = blk & 1;
  const int pix = (blk >> 1) * 256 + threadIdx.x;
  const int b = pix / kHW;
  const int pp = pix - b * kHW;
  const int h = pp / kW;
  const int w = pp - h * kW;
  const float gv = b3[0] + g[pix];
  if (tg == 0) {
    tap_project<0, 4>(pix, b, h, w, gv, win01, feat0, vox0, feat1, vox1, M0,
                      A1, sb, wsum, yp);
  } else {
    tap_project<4, 5>(pix, b, h, w, gv, win01, feat0, vox0, feat1, vox1, M0,
                      A1, sb, wsum, yp);
  }
}

// ---------------------------------------------------------------------------
// fused stencil+sigmoid+multiply, att-in-register:
// block <-> (256-granule chunk, channel HALF). thread <-> granule.
// x loads plain (L3-resident after k2); out stores nontemporal.
// ---------------------------------------------------------------------------
__global__ __launch_bounds__(256) void kpass2(const float* __restrict__ x_rgb,
                                              const float* __restrict__ yp,
                                              const float* __restrict__ bsp,
                                              float* __restrict__ out) {
  const int bid = blockIdx.x;
  const int q = bid / kChunks;         // channel half 0..1 (uniform/block)
  const int chunk = bid - q * kChunks;
  const int gran = chunk * 256 + threadIdx.x;
  const int b = gran / kHW4;
  const int p4 = gran - b * kHW4;
  const int h = p4 / kW4g;
  const int w4 = p4 - h * kW4g;

  const float bias = bsp[0];
  float4 lg = make_float4(bias, bias, bias, bias);
#pragma unroll
  for (int r = 0; r < 3; ++r) {
    const size_t rowoff = ((size_t)h + r) * kPW + 4 * w4;
    const float* pA = yp + (size_t)((3 * r + 0) * kB + b) * kPlane + rowoff;
    const float* pB = yp + (size_t)((3 * r + 1) * kB + b) * kPlane + rowoff;
    const float* pC = yp + (size_t)((3 * r + 2) * kB + b) * kPlane + rowoff;
    float LA = pA[3];
    float4 a4 = *(const float4*)(pA + 4);
    float4 b4 = *(const float4*)(pB + 4);
    float4 c4 = *(const float4*)(pC + 4);
    float RC = pC[8];
    lg.x += LA + b4.x + c4.y;
    lg.y += a4.x + b4.y + c4.z;
    lg.z += a4.y + b4.z + c4.w;
    lg.w += a4.z + b4.w + RC;
  }
  float4 att;
  att.x = 1.f / (1.f + __expf(-lg.x));
  att.y = 1.f / (1.f + __expf(-lg.y));
  att.z = 1.f / (1.f + __expf(-lg.z));
  att.w = 1.f / (1.f + __expf(-lg.w));

  const float4* xr = (const float4*)(x_rgb + (size_t)b * kC * kHW) + p4;
  vf4* op = (vf4*)(out + (size_t)b * kC * kHW) + p4;
#pragma unroll
  for (int cc = 0; cc < 32; ++cc) {
    const int c = q * 32 + cc;
    float4 x4 = xr[(size_t)c * kHW4];
    vf4 r4;
    r4.x = x4.x * att.x;
    r4.y = x4.y * att.y;
    r4.z = x4.z * att.z;
    r4.w = x4.w * att.w;
    __builtin_nontemporal_store(r4, op + (size_t)c * kHW4);
  }
}

}  // namespace

extern "C" void kernel_launch(void* const* d_in, const int* in_sizes, int n_in,
                              void* d_out, int out_size, void* d_ws,
                              size_t ws_size, hipStream_t stream) {
  const float* x_rgb = (const float*)d_in[0];
  const float* feat0 = (const float*)d_in[1];
  const float* coor0 = (const float*)d_in[2];
  const float* vox0 = (const float*)d_in[3];
  const float* feat1 = (const float*)d_in[4];
  const float* coor1 = (const float*)d_in[5];
  const float* vox1 = (const float*)d_in[6];
  const float* W0 = (const float*)d_in[7];
  const float* b0 = (const float*)d_in[8];
  const float* W2 = (const float*)d_in[9];
  const float* b2 = (const float*)d_in[10];
  const float* W3 = (const float*)d_in[11];
  const float* b3 = (const float*)d_in[12];
  const float* Wsp = (const float*)d_in[13];
  const float* bsp = (const float*)d_in[14];
  float* out = (float*)d_out;

  // workspace: yp[18*194*648] | g[BHW] | win01[2*BHW] | M0 | A1 | sb | wsum
  float* yp = (float*)d_ws;
  float* g = yp + (size_t)kYPF;
  int* win01 = (int*)(g + (size_t)kBHW);
  float* M0 = (float*)(win01 + (size_t)2 * kBHW);
  float* A1 = M0 + 9 * 35;
  float* sb = A1 + 9 * kCL;
  float* wsum = sb + 9;

  const int ninit = kBordTot + kWin4;
  kinit<<<(ninit + 255) / 256, 256, 0, stream>>>(yp, (int4*)win01);
  k2<<<kPrecB + 1, 256, 0, stream>>>(coor0, coor1, win01, W0, b0, W2, b2, Wsp,
                                     M0, A1, sb, wsum, x_rgb, W3, g);
  kgy<<<2 * kBHW / 256, 256, 0, stream>>>(g, (const int2*)win01, feat0, vox0,
                                          feat1, vox1, M0, A1, sb, wsum, b3,
                                          yp);
  kpass2<<<2 * kChunks, 256, 0, stream>>>(x_rgb, yp, bsp, out);
}

// Round 20
// 69.798 us; speedup vs baseline: 1.1251x; 1.0241x over previous
//
#include <hip/hip_runtime.h>

namespace {
constexpr int kH = 192, kW = 640, kHW = kH * kW;
constexpr int kW4g = kW / 4;            // 160 granules per row
constexpr int kHW4 = kHW / 4;           // 30720 granules per plane
constexpr int kB = 2, kC = 64;          // batch, image channels
constexpr int kN0 = 40000, kC0 = 32;    // level0 points/channels
constexpr int kN1 = 20000, kC1 = 64;    // level1 points/channels
constexpr int kCL = 67;                 // C1 + 3
constexpr int kBHW = kB * kHW;
// zero-padded y planes: 18 = 9 taps x B, rows H+2, pitch W+8 (interior at +1,+4)
constexpr int kPH = kH + 2, kPW = kW + 8;  // 194 x 648
constexpr int kPW4 = kPW / 4;              // 162
constexpr int kPlane = kPH * kPW;          // 125712
constexpr int kYPF = 18 * kPlane;
constexpr int kWin4 = 2 * kBHW / 4;        // win01 int2 array as int4 pairs
// border float4s per plane: row0 (162) + row193 (162) + 192 rows x {col0,col161}
constexpr int kBord = 162 + 162 + 192 * 2;  // 708
constexpr int kBordTot = 18 * kBord;        // 12744
// K2 block partition: gate FIRST (BW-critical, 8-way channel split for
// 30 waves/CU), then scatter, then precomp
constexpr int kGateB = kB * kHW4 / 32;      // 1920 gate blocks (32 gran/blk)
constexpr int kScatB0 = kGateB;             // scatter starts at 1920
constexpr int kScatB = 469;                 // ceil(120000/256)
constexpr int kPrecB = kScatB0 + kScatB;    // 2389 = precomp block
// kpass2 partition: 240 granule-chunks x 2 channel-halves
constexpr int kChunks = kB * kHW4 / 256;    // 240

typedef float vf4 __attribute__((ext_vector_type(4)));

// ---------------------------------------------------------------------------
// init: zero ONLY the padded-y borders (interior is fully rewritten by kgy
// each replay) and fill the interleaved winner map with -1.
// ---------------------------------------------------------------------------
__global__ __launch_bounds__(256) void kinit(float* __restrict__ yp,
                                             int4* __restrict__ win4) {
  int i = blockIdx.x * 256 + threadIdx.x;
  if (i < kBordTot) {
    int plane = i / kBord, r = i - plane * kBord;
    float4* base = (float4*)(yp + (size_t)plane * kPlane);
    int f4;
    if (r < 162) {
      f4 = r;                                  // row 0
    } else if (r < 324) {
      f4 = 193 * kPW4 + (r - 162);             // row 193
    } else {
      int rr = r - 324;
      int row = 1 + (rr >> 1);
      f4 = row * kPW4 + ((rr & 1) ? (kPW4 - 1) : 0);  // cols 0-3 / 644-647
    }
    base[f4] = make_float4(0.f, 0.f, 0.f, 0.f);
  } else {
    int j = i - kBordTot;
    if (j < kWin4) win4[j] = make_int4(-1, -1, -1, -1);
  }
}

// ---------------------------------------------------------------------------
// K2 (heterogeneous; gate first so the BW-critical 63 MB stream opens at
// dispatch time, scatter+precomp hide in its tail):
//   blocks [0,1920): gate -> single summed g plane. Block = 32 granules;
//        256 thr = 32 granules x 8 chunks of 8 ch; LDS-reduce (fixed order).
//        (8-way split: 30 waves/CU during the stream vs 15 at 4-way.)
//   blocks [1920,2389): winner scatter into interleaved win01 (int2/pixel,
//        last-write-wins == max index wins)
//   block 2389: LDS-staged fold: b'=W2@b0+b2; A1=Wsp^T@W2; M0=A1@W0;
//        sb_k=Wsp[:,k].b'; wsum_k=sum_c Wsp[c,k]
// ---------------------------------------------------------------------------
__global__ __launch_bounds__(256) void k2(
    const float* __restrict__ coor0, const float* __restrict__ coor1,
    int* __restrict__ win01,
    const float* __restrict__ W0, const float* __restrict__ b0,
    const float* __restrict__ W2, const float* __restrict__ b2,
    const float* __restrict__ Wsp, float* __restrict__ M0,
    float* __restrict__ A1g, float* __restrict__ sb, float* __restrict__ wsum,
    const float* __restrict__ x_rgb, const float* __restrict__ W3,
    float* __restrict__ g) {
  __shared__ float W2s[kCL * kCL];
  __shared__ float W0s[kCL * 35];
  __shared__ float Wsps[kCL * 9];
  __shared__ float A1s[9 * kCL];
  __shared__ float bps[kCL];
  const int bid = blockIdx.x;
  const int t = threadIdx.x;
  if (bid < kGateB) {  // ---- gate ----
    __shared__ float4 part[8][32];
    const int gg = t & 31, q = t >> 5;  // granule 0..31, chunk 0..7
    const int gran = bid * 32 + gg;
    const int b = gran / kHW4;
    const int p4 = gran - b * kHW4;
    const float4* xr = (const float4*)(x_rgb + (size_t)b * kC * kHW) + p4;
    float4 acc = make_float4(0.f, 0.f, 0.f, 0.f);
#pragma unroll
    for (int cc = 0; cc < 8; ++cc) {
      const int c = q * 8 + cc;
      float wv = W3[c];
      float4 x4 = xr[(size_t)c * kHW4];
      acc.x += wv * x4.x;
      acc.y += wv * x4.y;
      acc.z += wv * x4.z;
      acc.w += wv * x4.w;
    }
    part[q][gg] = acc;
    __syncthreads();
    if (t < 32) {
      float4 s = part[0][t];
#pragma unroll
      for (int q2 = 1; q2 < 8; ++q2) {
        float4 p = part[q2][t];
        s.x += p.x;
        s.y += p.y;
        s.z += p.z;
        s.w += p.w;
      }
      ((float4*)g)[bid * 32 + t] = s;
    }
    return;
  }
  if (bid < kPrecB) {  // ---- scatter ----
    int idx = (bid - kScatB0) * 256 + t;
    const float* coor;
    int lvl, N;
    if (idx < kB * kN0) {
      coor = coor0; lvl = 0; N = kN0;
    } else {
      idx -= kB * kN0;
      if (idx >= kB * kN1) return;
      coor = coor1; lvl = 1; N = kN1;
    }
    int b = idx / N;
    float u = coor[(size_t)idx * 2 + 0];
    float v = coor[(size_t)idx * 2 + 1];
    u = fminf(fmaxf(u, 0.f), 1.f);
    v = fminf(fmaxf(v, 0.f), 1.f);
    int r = (int)(v * (float)kH);  // row from coor[:,1]
    int c = (int)(u * (float)kW);  // col from coor[:,0]
    if (r < kH && c < kW) {
      int n = idx - b * N;
      atomicMax(&win01[2 * (b * kHW + r * kW + c) + lvl], n);
    }
    return;
  }
  // ---- precomp (block 2389, LDS-staged) ----
  for (int i = t; i < kCL * kCL; i += 256) W2s[i] = W2[i];
  for (int i = t; i < kCL * 35; i += 256) W0s[i] = W0[i];
  for (int i = t; i < kCL * 9; i += 256) Wsps[i] = Wsp[i];
  __syncthreads();
  if (t < kCL) {
    float s = b2[t];
    for (int j = 0; j < kCL; ++j) s += W2s[t * kCL + j] * b0[j];
    bps[t] = s;
  }
  for (int idx = t; idx < 9 * kCL; idx += 256) {
    int k = idx / kCL, j = idx - k * kCL;
    float s = 0.f;
    for (int c = 0; c < kCL; ++c) s += Wsps[c * 9 + k] * W2s[c * kCL + j];
    A1s[idx] = s;
    A1g[idx] = s;
  }
  __syncthreads();
  for (int idx = t; idx < 9 * 35; idx += 256) {
    int k = idx / 35, i = idx - k * 35;
    float s = 0.f;
    for (int j = 0; j < kCL; ++j) s += A1s[k * kCL + j] * W0s[j * 35 + i];
    M0[idx] = s;
  }
  if (t < 9) {
    float s = 0.f;
    for (int c = 0; c < kCL; ++c) s += Wsps[c * 9 + t] * bps[c];
    sb[t] = s;
  } else if (t >= 16 && t < 25) {
    int k = t - 16;
    float s = 0.f;
    for (int c = 0; c < kCL; ++c) s += Wsps[c * 9 + k];
    wsum[k] = s;
  }
}

// ---------------------------------------------------------------------------
// kgy: 3-way tap-split (2880 blocks = 45 waves/CU, saturated -- the proven
// optimum from the r17/r18/r19 split-factor A/B). Winners as one int2/pixel;
// weights as wave-uniform global loads (SGPR-served).
// ---------------------------------------------------------------------------
__global__ __launch_bounds__(256) void kgy(
    const float* __restrict__ g, const int2* __restrict__ win01,
    const float* __restrict__ feat0, const float* __restrict__ vox0,
    const float* __restrict__ feat1, const float* __restrict__ vox1,
    const float* __restrict__ M0, const float* __restrict__ A1,
    const float* __restrict__ sb, const float* __restrict__ wsum,
    const float* __restrict__ b3, float* __restrict__ yp) {
  const int blk = blockIdx.x;
  const int tg = blk % 3;              // tap row group: taps 3tg..3tg+2
  const int pix = (blk / 3) * 256 + threadIdx.x;
  const int b = pix / kHW;
  const int pp = pix - b * kHW;
  const int h = pp / kW;
  const int w = pp - h * kW;
  const float gv = b3[0] + g[pix];
  float y[3];
#pragma unroll
  for (int kk = 0; kk < 3; ++kk)
    y[kk] = wsum[3 * tg + kk] * gv + sb[3 * tg + kk];

  const int2 wv2 = win01[pix];
  const int w0 = wv2.x;
  if (w0 >= 0) {
    const float4* f0 = (const float4*)(feat0 + ((size_t)b * kN0 + w0) * kC0);
#pragma unroll
    for (int i4 = 0; i4 < 8; ++i4) {
      float4 v = f0[i4];
#pragma unroll
      for (int kk = 0; kk < 3; ++kk) {
        const float* m = M0 + (3 * tg + kk) * 35 + i4 * 4;
        y[kk] += m[0] * v.x + m[1] * v.y + m[2] * v.z + m[3] * v.w;
      }
    }
    const float* v0 = vox0 + ((size_t)b * kN0 + w0) * 3;
#pragma unroll
    for (int i = 0; i < 3; ++i) {
      float v = v0[i];
#pragma unroll
      for (int kk = 0; kk < 3; ++kk)
        y[kk] += M0[(3 * tg + kk) * 35 + kC0 + i] * v;
    }
  }
  const int w1 = wv2.y;
  if (w1 >= 0) {
    const float4* f1 = (const float4*)(feat1 + ((size_t)b * kN1 + w1) * kC1);
#pragma unroll
    for (int i4 = 0; i4 < 16; ++i4) {
      float4 v = f1[i4];
#pragma unroll
      for (int kk = 0; kk < 3; ++kk) {
        const float* m = A1 + (3 * tg + kk) * kCL + i4 * 4;
        y[kk] += m[0] * v.x + m[1] * v.y + m[2] * v.z + m[3] * v.w;
      }
    }
    const float* v1 = vox1 + ((size_t)b * kN1 + w1) * 3;
#pragma unroll
    for (int i = 0; i < 3; ++i) {
      float v = v1[i];
#pragma unroll
      for (int kk = 0; kk < 3; ++kk)
        y[kk] += A1[(3 * tg + kk) * kCL + kC1 + i] * v;
    }
  }
#pragma unroll
  for (int kk = 0; kk < 3; ++kk) {
    yp[((size_t)((3 * tg + kk) * kB + b) * kPH + (h + 1)) * kPW + 4 + w] =
        y[kk];
  }
}

// ---------------------------------------------------------------------------
// fused stencil+sigmoid+multiply, att-in-register:
// block <-> (256-granule chunk, channel HALF). thread <-> granule.
// x loads plain (L3-resident after k2); out stores nontemporal.
// ---------------------------------------------------------------------------
__global__ __launch_bounds__(256) void kpass2(const float* __restrict__ x_rgb,
                                              const float* __restrict__ yp,
                                              const float* __restrict__ bsp,
                                              float* __restrict__ out) {
  const int bid = blockIdx.x;
  const int q = bid / kChunks;         // channel half 0..1 (uniform/block)
  const int chunk = bid - q * kChunks;
  const int gran = chunk * 256 + threadIdx.x;
  const int b = gran / kHW4;
  const int p4 = gran - b * kHW4;
  const int h = p4 / kW4g;
  const int w4 = p4 - h * kW4g;

  const float bias = bsp[0];
  float4 lg = make_float4(bias, bias, bias, bias);
#pragma unroll
  for (int r = 0; r < 3; ++r) {
    const size_t rowoff = ((size_t)h + r) * kPW + 4 * w4;
    const float* pA = yp + (size_t)((3 * r + 0) * kB + b) * kPlane + rowoff;
    const float* pB = yp + (size_t)((3 * r + 1) * kB + b) * kPlane + rowoff;
    const float* pC = yp + (size_t)((3 * r + 2) * kB + b) * kPlane + rowoff;
    float LA = pA[3];
    float4 a4 = *(const float4*)(pA + 4);
    float4 b4 = *(const float4*)(pB + 4);
    float4 c4 = *(const float4*)(pC + 4);
    float RC = pC[8];
    lg.x += LA + b4.x + c4.y;
    lg.y += a4.x + b4.y + c4.z;
    lg.z += a4.y + b4.z + c4.w;
    lg.w += a4.z + b4.w + RC;
  }
  float4 att;
  att.x = 1.f / (1.f + __expf(-lg.x));
  att.y = 1.f / (1.f + __expf(-lg.y));
  att.z = 1.f / (1.f + __expf(-lg.z));
  att.w = 1.f / (1.f + __expf(-lg.w));

  const float4* xr = (const float4*)(x_rgb + (size_t)b * kC * kHW) + p4;
  vf4* op = (vf4*)(out + (size_t)b * kC * kHW) + p4;
#pragma unroll
  for (int cc = 0; cc < 32; ++cc) {
    const int c = q * 32 + cc;
    float4 x4 = xr[(size_t)c * kHW4];
    vf4 r4;
    r4.x = x4.x * att.x;
    r4.y = x4.y * att.y;
    r4.z = x4.z * att.z;
    r4.w = x4.w * att.w;
    __builtin_nontemporal_store(r4, op + (size_t)c * kHW4);
  }
}

}  // namespace

extern "C" void kernel_launch(void* const* d_in, const int* in_sizes, int n_in,
                              void* d_out, int out_size, void* d_ws,
                              size_t ws_size, hipStream_t stream) {
  const float* x_rgb = (const float*)d_in[0];
  const float* feat0 = (const float*)d_in[1];
  const float* coor0 = (const float*)d_in[2];
  const float* vox0 = (const float*)d_in[3];
  const float* feat1 = (const float*)d_in[4];
  const float* coor1 = (const float*)d_in[5];
  const float* vox1 = (const float*)d_in[6];
  const float* W0 = (const float*)d_in[7];
  const float* b0 = (const float*)d_in[8];
  const float* W2 = (const float*)d_in[9];
  const float* b2 = (const float*)d_in[10];
  const float* W3 = (const float*)d_in[11];
  const float* b3 = (const float*)d_in[12];
  const float* Wsp = (const float*)d_in[13];
  const float* bsp = (const float*)d_in[14];
  float* out = (float*)d_out;

  // workspace: yp[18*194*648] | g[BHW] | win01[2*BHW] | M0 | A1 | sb | wsum
  float* yp = (float*)d_ws;
  float* g = yp + (size_t)kYPF;
  int* win01 = (int*)(g + (size_t)kBHW);
  float* M0 = (float*)(win01 + (size_t)2 * kBHW);
  float* A1 = M0 + 9 * 35;
  float* sb = A1 + 9 * kCL;
  float* wsum = sb + 9;

  const int ninit = kBordTot + kWin4;
  kinit<<<(ninit + 255) / 256, 256, 0, stream>>>(yp, (int4*)win01);
  k2<<<kPrecB + 1, 256, 0, stream>>>(coor0, coor1, win01, W0, b0, W2, b2, Wsp,
                                     M0, A1, sb, wsum, x_rgb, W3, g);
  kgy<<<3 * kBHW / 256, 256, 0, stream>>>(g, (const int2*)win01, feat0, vox0,
                                          feat1, vox1, M0, A1, sb, wsum, b3,
                                          yp);
  kpass2<<<2 * kChunks, 256, 0, stream>>>(x_rgb, yp, bsp, out);
}

// Round 21
// 67.445 us; speedup vs baseline: 1.1643x; 1.0349x over previous
//
#include <hip/hip_runtime.h>

namespace {
constexpr int kH = 192, kW = 640, kHW = kH * kW;
constexpr int kW4g = kW / 4;            // 160 granules per row
constexpr int kHW4 = kHW / 4;           // 30720 granules per plane
constexpr int kB = 2, kC = 64;          // batch, image channels
constexpr int kN0 = 40000, kC0 = 32;    // level0 points/channels
constexpr int kN1 = 20000, kC1 = 64;    // level1 points/channels
constexpr int kCL = 67;                 // C1 + 3
constexpr int kBHW = kB * kHW;
// zero-padded y planes: 18 = 9 taps x B, rows H+2, pitch W+8 (interior at +1,+4)
constexpr int kPH = kH + 2, kPW = kW + 8;  // 194 x 648
constexpr int kPW4 = kPW / 4;              // 162
constexpr int kPlane = kPH * kPW;          // 125712
constexpr int kYPF = 18 * kPlane;
constexpr int kWin4 = 2 * kBHW / 4;        // win01 int2 array as int4 pairs
// border float4s per plane: row0 (162) + row193 (162) + 192 rows x {col0,col161}
constexpr int kBord = 162 + 162 + 192 * 2;  // 708
constexpr int kBordTot = 18 * kBord;        // 12744
// K2 block partition: precomp block 0 (starts immediately, concurrent with
// gate); gate blocks 1..960 (BW-critical 63 MB stream); scatter next
// (latency-tolerant, fills gate tail); yp-border zeroing last (order-free).
constexpr int kGateB0 = 1;
constexpr int kGateB = kB * kHW4 / 64;      // 960 gate blocks (64 gran/blk)
constexpr int kScatB0 = kGateB0 + kGateB;   // 961
constexpr int kScatB = 469;                 // ceil(120000/256)
constexpr int kBordB0 = kScatB0 + kScatB;   // 1430
constexpr int kBordB = (kBordTot + 255) / 256;  // 50
constexpr int kK2B = kBordB0 + kBordB;      // 1480 blocks total
// kpass2 partition: 240 granule-chunks x 2 channel-halves
constexpr int kChunks = kB * kHW4 / 256;    // 240

typedef float vf4 __attribute__((ext_vector_type(4)));

// ---------------------------------------------------------------------------
// kinit: fill the interleaved winner map with -1 (needed before k2's
// scatter atomicMax). yp-border zeroing moved into k2 (order-free there).
// ---------------------------------------------------------------------------
__global__ __launch_bounds__(256) void kinit(int4* __restrict__ win4) {
  int i = blockIdx.x * 256 + threadIdx.x;
  if (i < kWin4) win4[i] = make_int4(-1, -1, -1, -1);
}

// ---------------------------------------------------------------------------
// K2 (heterogeneous, all parts independent given win init):
//   block 0: LDS-staged fold: b'=W2@b0+b2; A1=Wsp^T@W2 [9,67]; M0=A1@W0
//        [9,35]; sb_k=Wsp[:,k].b'; wsum_k=sum_c Wsp[c,k]
//        (block 0 so it starts at dispatch -- as the LAST block (r17..r20)
//        it ran as a ~5us serial tail on a drained GPU before kgy)
//   blocks [1,961): gate -> single summed g plane. Block = 64 granules;
//        256 thr = 64 granules x 4 chunks of 16 ch; LDS-reduce (fixed order).
//   blocks [961,1430): winner scatter into interleaved win01 (int2/pixel,
//        last-write-wins == max index wins)
//   blocks [1430,1480): zero the padded-y borders (read only by kpass2)
// ---------------------------------------------------------------------------
__global__ __launch_bounds__(256) void k2(
    const float* __restrict__ coor0, const float* __restrict__ coor1,
    int* __restrict__ win01,
    const float* __restrict__ W0, const float* __restrict__ b0,
    const float* __restrict__ W2, const float* __restrict__ b2,
    const float* __restrict__ Wsp, float* __restrict__ M0,
    float* __restrict__ A1g, float* __restrict__ sb, float* __restrict__ wsum,
    const float* __restrict__ x_rgb, const float* __restrict__ W3,
    float* __restrict__ g, float* __restrict__ yp) {
  __shared__ float W2s[kCL * kCL];
  __shared__ float W0s[kCL * 35];
  __shared__ float Wsps[kCL * 9];
  __shared__ float A1s[9 * kCL];
  __shared__ float bps[kCL];
  const int bid = blockIdx.x;
  const int t = threadIdx.x;
  if (bid >= kGateB0 && bid < kScatB0) {  // ---- gate ----
    __shared__ float4 part[4][64];
    const int gg = t & 63, q = t >> 6;
    const int gran = (bid - kGateB0) * 64 + gg;
    const int b = gran / kHW4;
    const int p4 = gran - b * kHW4;
    const float4* xr = (const float4*)(x_rgb + (size_t)b * kC * kHW) + p4;
    float4 acc = make_float4(0.f, 0.f, 0.f, 0.f);
#pragma unroll
    for (int cc = 0; cc < 16; ++cc) {
      const int c = q * 16 + cc;
      float wv = W3[c];
      float4 x4 = xr[(size_t)c * kHW4];
      acc.x += wv * x4.x;
      acc.y += wv * x4.y;
      acc.z += wv * x4.z;
      acc.w += wv * x4.w;
    }
    part[q][gg] = acc;
    __syncthreads();
    if (t < 64) {
      float4 p0 = part[0][t], p1 = part[1][t], p2 = part[2][t],
             p3 = part[3][t];
      float4 s;
      s.x = p0.x + p1.x + p2.x + p3.x;
      s.y = p0.y + p1.y + p2.y + p3.y;
      s.z = p0.z + p1.z + p2.z + p3.z;
      s.w = p0.w + p1.w + p2.w + p3.w;
      ((float4*)g)[(bid - kGateB0) * 64 + t] = s;
    }
    return;
  }
  if (bid >= kScatB0 && bid < kBordB0) {  // ---- scatter ----
    int idx = (bid - kScatB0) * 256 + t;
    const float* coor;
    int lvl, N;
    if (idx < kB * kN0) {
      coor = coor0; lvl = 0; N = kN0;
    } else {
      idx -= kB * kN0;
      if (idx >= kB * kN1) return;
      coor = coor1; lvl = 1; N = kN1;
    }
    int b = idx / N;
    float u = coor[(size_t)idx * 2 + 0];
    float v = coor[(size_t)idx * 2 + 1];
    u = fminf(fmaxf(u, 0.f), 1.f);
    v = fminf(fmaxf(v, 0.f), 1.f);
    int r = (int)(v * (float)kH);  // row from coor[:,1]
    int c = (int)(u * (float)kW);  // col from coor[:,0]
    if (r < kH && c < kW) {
      int n = idx - b * N;
      atomicMax(&win01[2 * (b * kHW + r * kW + c) + lvl], n);
    }
    return;
  }
  if (bid >= kBordB0) {  // ---- yp border zeroing ----
    int i = (bid - kBordB0) * 256 + t;
    if (i < kBordTot) {
      int plane = i / kBord, r = i - plane * kBord;
      float4* base = (float4*)(yp + (size_t)plane * kPlane);
      int f4;
      if (r < 162) {
        f4 = r;                                  // row 0
      } else if (r < 324) {
        f4 = 193 * kPW4 + (r - 162);             // row 193
      } else {
        int rr = r - 324;
        int row = 1 + (rr >> 1);
        f4 = row * kPW4 + ((rr & 1) ? (kPW4 - 1) : 0);  // cols 0-3 / 644-647
      }
      base[f4] = make_float4(0.f, 0.f, 0.f, 0.f);
    }
    return;
  }
  // ---- precomp (block 0, LDS-staged) ----
  for (int i = t; i < kCL * kCL; i += 256) W2s[i] = W2[i];
  for (int i = t; i < kCL * 35; i += 256) W0s[i] = W0[i];
  for (int i = t; i < kCL * 9; i += 256) Wsps[i] = Wsp[i];
  __syncthreads();
  if (t < kCL) {
    float s = b2[t];
    for (int j = 0; j < kCL; ++j) s += W2s[t * kCL + j] * b0[j];
    bps[t] = s;
  }
  for (int idx = t; idx < 9 * kCL; idx += 256) {
    int k = idx / kCL, j = idx - k * kCL;
    float s = 0.f;
    for (int c = 0; c < kCL; ++c) s += Wsps[c * 9 + k] * W2s[c * kCL + j];
    A1s[idx] = s;
    A1g[idx] = s;
  }
  __syncthreads();
  for (int idx = t; idx < 9 * 35; idx += 256) {
    int k = idx / 35, i = idx - k * 35;
    float s = 0.f;
    for (int j = 0; j < kCL; ++j) s += A1s[k * kCL + j] * W0s[j * 35 + i];
    M0[idx] = s;
  }
  if (t < 9) {
    float s = 0.f;
    for (int c = 0; c < kCL; ++c) s += Wsps[c * 9 + t] * bps[c];
    sb[t] = s;
  } else if (t >= 16 && t < 25) {
    int k = t - 16;
    float s = 0.f;
    for (int c = 0; c < kCL; ++c) s += Wsps[c * 9 + k];
    wsum[k] = s;
  }
}

// ---------------------------------------------------------------------------
// kgy: 3-way tap-split (2880 blocks = 45 waves/CU, saturated -- the proven
// optimum from the r17/r18/r19 split-factor A/B). Winners as one int2/pixel;
// weights as wave-uniform global loads (SGPR-served).
// ---------------------------------------------------------------------------
__global__ __launch_bounds__(256) void kgy(
    const float* __restrict__ g, const int2* __restrict__ win01,
    const float* __restrict__ feat0, const float* __restrict__ vox0,
    const float* __restrict__ feat1, const float* __restrict__ vox1,
    const float* __restrict__ M0, const float* __restrict__ A1,
    const float* __restrict__ sb, const float* __restrict__ wsum,
    const float* __restrict__ b3, float* __restrict__ yp) {
  const int blk = blockIdx.x;
  const int tg = blk % 3;              // tap row group: taps 3tg..3tg+2
  const int pix = (blk / 3) * 256 + threadIdx.x;
  const int b = pix / kHW;
  const int pp = pix - b * kHW;
  const int h = pp / kW;
  const int w = pp - h * kW;
  const float gv = b3[0] + g[pix];
  float y[3];
#pragma unroll
  for (int kk = 0; kk < 3; ++kk)
    y[kk] = wsum[3 * tg + kk] * gv + sb[3 * tg + kk];

  const int2 wv2 = win01[pix];
  const int w0 = wv2.x;
  if (w0 >= 0) {
    const float4* f0 = (const float4*)(feat0 + ((size_t)b * kN0 + w0) * kC0);
#pragma unroll
    for (int i4 = 0; i4 < 8; ++i4) {
      float4 v = f0[i4];
#pragma unroll
      for (int kk = 0; kk < 3; ++kk) {
        const float* m = M0 + (3 * tg + kk) * 35 + i4 * 4;
        y[kk] += m[0] * v.x + m[1] * v.y + m[2] * v.z + m[3] * v.w;
      }
    }
    const float* v0 = vox0 + ((size_t)b * kN0 + w0) * 3;
#pragma unroll
    for (int i = 0; i < 3; ++i) {
      float v = v0[i];
#pragma unroll
      for (int kk = 0; kk < 3; ++kk)
        y[kk] += M0[(3 * tg + kk) * 35 + kC0 + i] * v;
    }
  }
  const int w1 = wv2.y;
  if (w1 >= 0) {
    const float4* f1 = (const float4*)(feat1 + ((size_t)b * kN1 + w1) * kC1);
#pragma unroll
    for (int i4 = 0; i4 < 16; ++i4) {
      float4 v = f1[i4];
#pragma unroll
      for (int kk = 0; kk < 3; ++kk) {
        const float* m = A1 + (3 * tg + kk) * kCL + i4 * 4;
        y[kk] += m[0] * v.x + m[1] * v.y + m[2] * v.z + m[3] * v.w;
      }
    }
    const float* v1 = vox1 + ((size_t)b * kN1 + w1) * 3;
#pragma unroll
    for (int i = 0; i < 3; ++i) {
      float v = v1[i];
#pragma unroll
      for (int kk = 0; kk < 3; ++kk)
        y[kk] += A1[(3 * tg + kk) * kCL + kC1 + i] * v;
    }
  }
#pragma unroll
  for (int kk = 0; kk < 3; ++kk) {
    yp[((size_t)((3 * tg + kk) * kB + b) * kPH + (h + 1)) * kPW + 4 + w] =
        y[kk];
  }
}

// ---------------------------------------------------------------------------
// fused stencil+sigmoid+multiply, att-in-register:
// block <-> (256-granule chunk, channel HALF). thread <-> granule.
// x loads plain (L3-resident after k2); out stores nontemporal.
// ---------------------------------------------------------------------------
__global__ __launch_bounds__(256) void kpass2(const float* __restrict__ x_rgb,
                                              const float* __restrict__ yp,
                                              const float* __restrict__ bsp,
                                              float* __restrict__ out) {
  const int bid = blockIdx.x;
  const int q = bid / kChunks;         // channel half 0..1 (uniform/block)
  const int chunk = bid - q * kChunks;
  const int gran = chunk * 256 + threadIdx.x;
  const int b = gran / kHW4;
  const int p4 = gran - b * kHW4;
  const int h = p4 / kW4g;
  const int w4 = p4 - h * kW4g;

  const float bias = bsp[0];
  float4 lg = make_float4(bias, bias, bias, bias);
#pragma unroll
  for (int r = 0; r < 3; ++r) {
    const size_t rowoff = ((size_t)h + r) * kPW + 4 * w4;
    const float* pA = yp + (size_t)((3 * r + 0) * kB + b) * kPlane + rowoff;
    const float* pB = yp + (size_t)((3 * r + 1) * kB + b) * kPlane + rowoff;
    const float* pC = yp + (size_t)((3 * r + 2) * kB + b) * kPlane + rowoff;
    float LA = pA[3];
    float4 a4 = *(const float4*)(pA + 4);
    float4 b4 = *(const float4*)(pB + 4);
    float4 c4 = *(const float4*)(pC + 4);
    float RC = pC[8];
    lg.x += LA + b4.x + c4.y;
    lg.y += a4.x + b4.y + c4.z;
    lg.z += a4.y + b4.z + c4.w;
    lg.w += a4.z + b4.w + RC;
  }
  float4 att;
  att.x = 1.f / (1.f + __expf(-lg.x));
  att.y = 1.f / (1.f + __expf(-lg.y));
  att.z = 1.f / (1.f + __expf(-lg.z));
  att.w = 1.f / (1.f + __expf(-lg.w));

  const float4* xr = (const float4*)(x_rgb + (size_t)b * kC * kHW) + p4;
  vf4* op = (vf4*)(out + (size_t)b * kC * kHW) + p4;
#pragma unroll
  for (int cc = 0; cc < 32; ++cc) {
    const int c = q * 32 + cc;
    float4 x4 = xr[(size_t)c * kHW4];
    vf4 r4;
    r4.x = x4.x * att.x;
    r4.y = x4.y * att.y;
    r4.z = x4.z * att.z;
    r4.w = x4.w * att.w;
    __builtin_nontemporal_store(r4, op + (size_t)c * kHW4);
  }
}

}  // namespace

extern "C" void kernel_launch(void* const* d_in, const int* in_sizes, int n_in,
                              void* d_out, int out_size, void* d_ws,
                              size_t ws_size, hipStream_t stream) {
  const float* x_rgb = (const float*)d_in[0];
  const float* feat0 = (const float*)d_in[1];
  const float* coor0 = (const float*)d_in[2];
  const float* vox0 = (const float*)d_in[3];
  const float* feat1 = (const float*)d_in[4];
  const float* coor1 = (const float*)d_in[5];
  const float* vox1 = (const float*)d_in[6];
  const float* W0 = (const float*)d_in[7];
  const float* b0 = (const float*)d_in[8];
  const float* W2 = (const float*)d_in[9];
  const float* b2 = (const float*)d_in[10];
  const float* W3 = (const float*)d_in[11];
  const float* b3 = (const float*)d_in[12];
  const float* Wsp = (const float*)d_in[13];
  const float* bsp = (const float*)d_in[14];
  float* out = (float*)d_out;

  // workspace: yp[18*194*648] | g[BHW] | win01[2*BHW] | M0 | A1 | sb | wsum
  float* yp = (float*)d_ws;
  float* g = yp + (size_t)kYPF;
  int* win01 = (int*)(g + (size_t)kBHW);
  float* M0 = (float*)(win01 + (size_t)2 * kBHW);
  float* A1 = M0 + 9 * 35;
  float* sb = A1 + 9 * kCL;
  float* wsum = sb + 9;

  kinit<<<(kWin4 + 255) / 256, 256, 0, stream>>>((int4*)win01);
  k2<<<kK2B, 256, 0, stream>>>(coor0, coor1, win01, W0, b0, W2, b2, Wsp, M0,
                               A1, sb, wsum, x_rgb, W3, g, yp);
  kgy<<<3 * kBHW / 256, 256, 0, stream>>>(g, (const int2*)win01, feat0, vox0,
                                          feat1, vox1, M0, A1, sb, wsum, b3,
                                          yp);
  kpass2<<<2 * kChunks, 256, 0, stream>>>(x_rgb, yp, bsp, out);
}